// Round 13
// baseline (279.741 us; speedup 1.0000x reference)
//
#include <hip/hip_runtime.h>
#include <hip/hip_bf16.h>

// Problem constants (fixed by setup_inputs)
constexpr int B = 4, Q = 100, C = 40, Cp1 = 41, HW = 65536;

// kOne geometry: one wave per 256-px segment, covering ALL 100 q (7 tiles of 16)
constexpr int SEGPX = 256;                  // px per wave
constexpr int SEGS_PER_B = HW / SEGPX;      // 256
constexpr int NSEG = B * SEGS_PER_B;        // 1024 waves
constexpr int OBLK = NSEG / 4;              // 256 blocks x 4 waves
constexpr int NSTEP = SEGPX / 32;           // 8 K-steps per wave
constexpr int NQT = 7;                      // q-tiles (rows 96..111 partially garbage)

// Workspace layout (4-byte words):
//  [0, 16000)        counts    u32 [B][Q][C]
//  [16000, 16160)    tsum      u32 [B][C]
//  [16160]           ce_sum    f32
//  [16161]           n_valid   u32
//  [16162, 32562)    inter_ext f32 [B*Q][41]   (col 40 = ignored-pixel sig sum)
constexpr int WS_WORDS = 32562;

typedef __attribute__((ext_vector_type(8))) short short8;   // 8 bf16
typedef __attribute__((ext_vector_type(4))) float f32x4;

__device__ __forceinline__ short f2bf(float f) {            // RNE f32->bf16
    unsigned u = __float_as_uint(f);
    u += 0x7FFF + ((u >> 16) & 1);
    return (short)(u >> 16);
}

__global__ void kZ(unsigned* __restrict__ ws, int n) {
    int i = blockIdx.x * blockDim.x + threadIdx.x;
    for (; i < n; i += gridDim.x * blockDim.x) ws[i] = 0u;
}

// SINGLE-PASS kernel: each wave reads its 256-px x 100-q slab of masks ONCE.
// From one load of each element: exp -> per-pixel LSE (pixel CE), per-pixel
// argmax + x[tgt] via 16-lane xor-butterflies, sigmoid -> bf16 -> one-hot MFMA
// (inter). Halves mask traffic vs the two-phase R11/R12 structure (which sat
// at ~2.9 TB/s aggregate delivered bytes).
__global__ __launch_bounds__(256) void kOne(const float* __restrict__ masks,
                                            const int* __restrict__ targets,
                                            unsigned* __restrict__ counts,
                                            unsigned* __restrict__ tsum,
                                            float* __restrict__ ce_sum,
                                            unsigned* __restrict__ n_valid,
                                            float* __restrict__ inter_ext) {
    __shared__ unsigned ts_local[C];
    __shared__ float cred[4];
    __shared__ unsigned vred[4];

    int tid = threadIdx.x;
    int lane = tid & 63, wave = tid >> 6;
    int m = lane & 15, quad = lane >> 4;

    int seg = blockIdx.x * 4 + wave;            // 0..1023
    int b = seg >> 8;                           // uniform per block (256%4==0)
    int k0 = (seg & 255) * SEGPX;

    const int* tp = targets + (size_t)b * HW + k0 + quad * 8;

    // per-qt plane index (clamp garbage rows of tile 6; masked out below)
    int plane[NQT];
    #pragma unroll
    for (int qt = 0; qt < NQT; ++qt) {
        int qa = qt * 16 + m;
        if (qa > 99) qa = 99;
        plane[qt] = b * Q + qa;
    }
    // one-hot compare values (constant per lane)
    int cv0 = m, cv1 = 16 + m;
    int cv2 = (m == 8) ? 255 : 32 + m;          // col 40 <- ignored pixels

    f32x4 acc[NQT][3];
    #pragma unroll
    for (int qt = 0; qt < NQT; ++qt)
        #pragma unroll
        for (int a = 0; a < 3; ++a)
            acc[qt][a] = (f32x4){0.f, 0.f, 0.f, 0.f};

    if (tid < C) ts_local[tid] = 0u;
    __syncthreads();

    float ce_acc = 0.f;
    unsigned nv = 0;

    for (int step = 0; step < NSTEP; ++step) {
        int k = k0 + quad * 8 + step * 32;
        int tk = step * 32;
        int4 t0 = *(const int4*)(tp + tk);
        int4 t1 = *(const int4*)(tp + tk + 4);
        int tss[8] = {t0.x, t0.y, t0.z, t0.w, t1.x, t1.y, t1.z, t1.w};

        short8 b0, b1, b2;                      // shared across all 7 q-tiles
        #pragma unroll
        for (int j = 0; j < 8; ++j) {
            b0[j] = (tss[j] == cv0) ? (short)0x3F80 : (short)0;
            b1[j] = (tss[j] == cv1) ? (short)0x3F80 : (short)0;
            b2[j] = (tss[j] == cv2) ? (short)0x3F80 : (short)0;
        }

        float sE[8], mx[8], xt[8];
        int ix[8];
        #pragma unroll
        for (int j = 0; j < 8; ++j) { sE[j] = 0.f; mx[j] = -INFINITY; xt[j] = 0.f; ix[j] = 0; }

        #pragma unroll
        for (int qt = 0; qt < NQT; ++qt) {
            const float* ap = masks + (size_t)plane[qt] * HW + k;
            float4 x0 = *(const float4*)(ap);
            float4 x1 = *(const float4*)(ap + 4);
            float xs[8] = {x0.x, x0.y, x0.z, x0.w, x1.x, x1.y, x1.z, x1.w};
            int q = qt * 16 + m;
            bool valid = (qt < 6) || (m < 4);   // q < 100
            short8 av;
            #pragma unroll
            for (int j = 0; j < 8; ++j) {
                float v = valid ? xs[j] : -INFINITY;
                float e = __expf(v);                               // |v|<=~6: f32-safe
                float sig = e * __builtin_amdgcn_rcpf(1.f + e);    // e=0 -> sig=0
                av[j] = f2bf(sig);
                sE[j] += e;
                bool gt = v > mx[j];                               // strict >: first max
                ix[j] = gt ? q : ix[j];
                mx[j] = gt ? v : mx[j];
                xt[j] += (q == tss[j]) ? v : 0.f;                  // tgt<40: only real q match
            }
            acc[qt][0] = __builtin_amdgcn_mfma_f32_16x16x32_bf16(av, b0, acc[qt][0], 0, 0, 0);
            acc[qt][1] = __builtin_amdgcn_mfma_f32_16x16x32_bf16(av, b1, acc[qt][1], 0, 0, 0);
            acc[qt][2] = __builtin_amdgcn_mfma_f32_16x16x32_bf16(av, b2, acc[qt][2], 0, 0, 0);
        }

        // per-pixel reduction across the 16 m-lanes of each quad
        #pragma unroll
        for (int j = 0; j < 8; ++j) {
            float s = sE[j], x = xt[j], mm = mx[j];
            int ii = ix[j];
            #pragma unroll
            for (int msk = 1; msk <= 8; msk <<= 1) {
                s += __shfl_xor(s, msk);
                x += __shfl_xor(x, msk);
                float om = __shfl_xor(mm, msk);
                int oi = __shfl_xor(ii, msk);
                bool take = (om > mm) || (om == mm && oi < ii);  // tie -> smaller q
                mm = take ? om : mm;
                ii = take ? oi : ii;
            }
            if (m == j) {                        // one writer per pixel
                int tgt = tss[j];
                if (tgt != 255) {
                    ce_acc += __logf(s) - x;
                    nv++;
                    atomicAdd(&counts[((size_t)b * Q + ii) * C + tgt], 1u);
                    atomicAdd(&ts_local[tgt], 1u);
                }
            }
        }
    }

    // block reductions: ce / n_valid / tsum
    for (int off = 32; off; off >>= 1) {
        ce_acc += __shfl_xor(ce_acc, off);
        nv += __shfl_xor(nv, off);
    }
    if (lane == 0) { cred[wave] = ce_acc; vred[wave] = nv; }
    __syncthreads();   // covers ts_local atomics too
    if (tid == 0) {
        atomicAdd(ce_sum, cred[0] + cred[1] + cred[2] + cred[3]);
        atomicAdd(n_valid, vred[0] + vred[1] + vred[2] + vred[3]);
    }
    if (tid < C) {
        unsigned t = ts_local[tid];
        if (t) atomicAdd(&tsum[b * C + tid], t);
    }

    // inter epilogue: D row = quad*4+reg (query), col = m (R11-verified layout)
    #pragma unroll
    for (int qt = 0; qt < NQT; ++qt) {
        #pragma unroll
        for (int reg = 0; reg < 4; ++reg) {
            int q = qt * 16 + quad * 4 + reg;
            if (q < 100) {
                size_t base = (size_t)(b * Q + q) * Cp1;
                atomicAdd(&inter_ext[base + m], acc[qt][0][reg]);
                atomicAdd(&inter_ext[base + 16 + m], acc[qt][1][reg]);
                if (m <= 8) atomicAdd(&inter_ext[base + 32 + m], acc[qt][2][reg]);
            }
        }
    }
}

// Kernel C: finalize (verified R11/R12). src_sum = row-sum of inter_ext's 41 cols.
__global__ __launch_bounds__(512) void kC(const float* __restrict__ logits,
                                          const unsigned* __restrict__ counts,
                                          const unsigned* __restrict__ tsum,
                                          const float* __restrict__ inter_ext,
                                          const float* __restrict__ ce_sum,
                                          const unsigned* __restrict__ n_valid,
                                          float* __restrict__ out) {
    int tid = threadIdx.x;
    __shared__ float dice_sum[C];
    __shared__ float ssum[B * Q];
    __shared__ float wred[8];
    __shared__ float s_lce;
    if (tid < C) dice_sum[tid] = 0.f;
    if (tid < B * Q) {
        const float* r = inter_ext + (size_t)tid * Cp1;
        float t = 0.f;
        #pragma unroll
        for (int c = 0; c < Cp1; ++c) t += r[c];
        ssum[tid] = t;
    }

    float ce_acc = 0.f;
    for (int i = tid; i < B * Q; i += 512) {
        const unsigned* cnt = counts + (size_t)i * C;
        unsigned best = 0;
        int tc = C;
        #pragma unroll
        for (int c = 0; c < C; ++c) {
            unsigned v = cnt[c];
            if (v > best) { best = v; tc = c; }
        }
        if (tc != C) {
            const float* lg = logits + (size_t)i * Cp1;
            float mm = -INFINITY, xt = 0.f;
            #pragma unroll
            for (int c = 0; c < Cp1; ++c) {
                float v = lg[c];
                mm = fmaxf(mm, v);
                if (c == tc) xt = v;
            }
            float ss = 0.f;
            #pragma unroll
            for (int c = 0; c < Cp1; ++c) ss += __expf(lg[c] - mm);
            float nll = mm + __logf(ss) - xt;
            float p = __expf(-nll);
            float om = 1.f - p;
            ce_acc += om * om * nll;
        }
    }
    for (int off = 32; off; off >>= 1) ce_acc += __shfl_xor(ce_acc, off);
    if ((tid & 63) == 0) wred[tid >> 6] = ce_acc;
    __syncthreads();
    if (tid == 0) {
        float t = 0.f;
        for (int w = 0; w < 8; ++w) t += wred[w];
        s_lce = t;
    }

    for (int i = tid; i < B * Q * C; i += 512) {
        int bq = i / C, c = i - bq * C;
        float denom = ssum[bq] + (float)tsum[(bq / Q) * C + c] + 1e-8f;
        atomicAdd(&dice_sum[c], 2.f * inter_ext[(size_t)bq * Cp1 + c] / denom);
    }
    __syncthreads();

    if (tid == 0) {
        float dl = 0.f;
        for (int c = 0; c < C; ++c) {
            unsigned ts = tsum[c] + tsum[C + c] + tsum[2 * C + c] + tsum[3 * C + c];
            if (ts > 0) dl += 1.f - dice_sum[c] * (1.f / (B * Q));
        }
        dl *= (1.f / C);
        float ce_mask = ce_sum[0] / fmaxf((float)n_valid[0], 1.f);
        float lce = s_lce * (1.f / (B * Q));
        out[0] = 2.f * lce + 5.f * ce_mask + 5.f * dl;
    }
}

extern "C" void kernel_launch(void* const* d_in, const int* in_sizes, int n_in,
                              void* d_out, int out_size, void* d_ws, size_t ws_size,
                              hipStream_t stream) {
    const float* logits  = (const float*)d_in[0];   // [B,Q,41] f32
    const float* masks   = (const float*)d_in[1];   // [B,Q,H,W] f32
    const int*   targets = (const int*)d_in[2];     // [B,H,W] int32
    float* out = (float*)d_out;                     // f32 scalar

    unsigned* ws        = (unsigned*)d_ws;
    unsigned* counts    = ws;                       // 16000 u32
    unsigned* tsum      = ws + 16000;               // 160 u32
    float*    ce_sum    = (float*)(ws + 16160);     // 1 f32
    unsigned* n_valid   = ws + 16161;               // 1 u32
    float*    inter_ext = (float*)(ws + 16162);     // 16400 f32

    kZ<<<64, 256, 0, stream>>>(ws, WS_WORDS);
    kOne<<<OBLK, 256, 0, stream>>>(masks, targets, counts, tsum, ce_sum, n_valid,
                                   inter_ext);
    kC<<<1, 512, 0, stream>>>(logits, counts, tsum, inter_ext, ce_sum, n_valid, out);
}